// Round 1
// baseline (1197.244 us; speedup 1.0000x reference)
//
#include <hip/hip_runtime.h>
#include <hip/hip_bf16.h>

// ---------------- problem constants ----------------
#define Bg 4096
#define Kn 32
#define Dd 768
#define Tt 64
#define Ee 16

// output layout (float offsets into d_out)
#define SZ_CLF  (4096u*64u*32u)        /* 8388608 */
#define SZ_BD   (4096u*768u)           /* 3145728 */
#define OFF_CLF  0u
#define OFF_SCAE (SZ_CLF)
#define OFF_GROE (OFF_SCAE + SZ_BD)
#define OFF_GNN  (OFF_GROE + SZ_BD)
#define OFF_SCAZ (OFF_GNN + SZ_BD)
#define OFF_GROZ (OFF_SCAZ + SZ_BD)
#define OFF_SCAQ (OFF_GROZ + SZ_BD)
#define OFF_GROQ (OFF_SCAQ + 4096u*16u)

// ---------------- small float4 helpers ----------------
__device__ __forceinline__ void add4(float4& a, const float4 b) {
    a.x += b.x; a.y += b.y; a.z += b.z; a.w += b.w;
}
__device__ __forceinline__ float4 div4(const float4 a, float d) {
    return make_float4(a.x / d, a.y / d, a.z / d, a.w / d);
}

// ---------------- 1. per-graph segment_min -> present bitmask ----------------
__global__ __launch_bounds__(256) void k_graphmin(const int* __restrict__ node_batch,
                                                  int* __restrict__ present) {
    int g = blockIdx.x * 256 + threadIdx.x;
    if (g >= Bg) return;
    const int* nb = node_batch + (size_t)g * Kn;
    int m = nb[0];
    #pragma unroll
    for (int n = 1; n < Kn; ++n) m = min(m, nb[n]);
    m = min(max(m, 0), 7);
    atomicOr(present, 1 << m);
}

// ---------------- 2. pooling (gnn/sca/gro means + gate sums + fixups) -------
__global__ __launch_bounds__(192) void k_pool(const float* __restrict__ node_rep,
                                              const int* __restrict__ node_batch,
                                              const int* __restrict__ scaffold_flag,
                                              const int* __restrict__ present_p,
                                              float* __restrict__ out,
                                              float* __restrict__ sca_gate,
                                              float* __restrict__ gro_gate) {
    __shared__ float red[256];
    const int g = blockIdx.x, tid = threadIdx.x;
    const int present = *present_p;
    const int* nb = node_batch + (size_t)g * Kn;

    unsigned mb = 0; int scnt = 0;
    #pragma unroll
    for (int n = 0; n < Kn; ++n) {
        int c = nb[n]; c = min(max(c, 0), 7);
        int bit = (present >> c) & 1;
        mb |= ((unsigned)bit) << n;
        scnt += bit;
    }

    const float4* rows = (const float4*)node_rep + (size_t)g * Kn * 192 + tid;
    float4 asum = make_float4(0, 0, 0, 0), ssum = asum, gsum = asum;
    #pragma unroll 8
    for (int n = 0; n < Kn; ++n) {
        float4 v = rows[(size_t)n * 192];
        add4(asum, v);
        if ((mb >> n) & 1) add4(ssum, v); else add4(gsum, v);
    }

    float cs = (float)max(scnt, 1);
    float cg = (float)max(Kn - scnt, 1);
    float4 gnn  = div4(asum, 32.0f);
    float4 srep = div4(ssum, cs);
    float4 grep = div4(gsum, cg);
    float4 ggate = gsum;
    if (scaffold_flag[g] == 0) { grep = srep; ggate = ssum; }

    // row-sum of (post-nosca) gro_rep for the ==0 fixup
    red[tid] = grep.x + grep.y + grep.z + grep.w;
    if (tid < 64) red[192 + tid] = 0.f;
    __syncthreads();
    for (int s = 128; s > 0; s >>= 1) {
        if (tid < s) red[tid] += red[tid + s];
        __syncthreads();
    }
    if (red[0] == 0.0f) grep = srep;

    const size_t o = (size_t)g * 192 + tid;
    ((float4*)(out + OFF_GNN ))[o] = gnn;
    ((float4*)(out + OFF_SCAE))[o] = srep;
    ((float4*)(out + OFF_GROE))[o] = grep;
    ((float4*)sca_gate)[o] = ssum;
    ((float4*)gro_gate)[o] = ggate;
}

// ---------------- 3. fp32 tiled GEMM: C[M,N] = act(A[M,768]) @ W[768,N] + b --
// TRANS: 0 = none, 1 = BN+ReLU on A elements.  CMODE: 0 = linear, 1 = expert interleave.
#define GBM 128
#define GBN 64
#define GBK 16
#define GLDA 132

template <int TRANS, int CMODE>
__global__ __launch_bounds__(256) void k_gemm(const float* __restrict__ A,
                                              const float* __restrict__ W,
                                              const float* __restrict__ bias,
                                              float* __restrict__ C, int N,
                                              const float* __restrict__ bn_inv,
                                              const float* __restrict__ bn_shift,
                                              int half) {
    __shared__ __align__(16) float As[GBK][GLDA];
    __shared__ __align__(16) float Bs[GBK][GBN];
    const int tid = threadIdx.x;
    const int m0 = blockIdx.x * GBM;
    const int n0 = blockIdx.y * GBN;
    const int kc  = (tid & 3) * 4;   // A: k-offset within tile
    const int ar0 = tid >> 2;        // A: row 0..63 (and +64)
    const int bkr = tid >> 4;        // B: k-row 0..15
    const int bnc = (tid & 15) * 4;  // B: col
    const int tm0 = (tid >> 4) * 8;  // micro-tile row base
    const int tn0 = (tid & 15) * 4;  // micro-tile col base

    float acc[8][4];
    #pragma unroll
    for (int i = 0; i < 8; ++i)
        #pragma unroll
        for (int j = 0; j < 4; ++j) acc[i][j] = 0.f;

    for (int k0 = 0; k0 < 768; k0 += GBK) {
        float4 va0 = *(const float4*)&A[(size_t)(m0 + ar0) * 768 + k0 + kc];
        float4 va1 = *(const float4*)&A[(size_t)(m0 + ar0 + 64) * 768 + k0 + kc];
        if (TRANS) {
            const int kb = k0 + kc;
            const float i0 = bn_inv[kb], i1 = bn_inv[kb+1], i2 = bn_inv[kb+2], i3 = bn_inv[kb+3];
            const float s0 = bn_shift[kb], s1 = bn_shift[kb+1], s2 = bn_shift[kb+2], s3 = bn_shift[kb+3];
            va0.x = fmaxf(fmaf(va0.x, i0, s0), 0.f);
            va0.y = fmaxf(fmaf(va0.y, i1, s1), 0.f);
            va0.z = fmaxf(fmaf(va0.z, i2, s2), 0.f);
            va0.w = fmaxf(fmaf(va0.w, i3, s3), 0.f);
            va1.x = fmaxf(fmaf(va1.x, i0, s0), 0.f);
            va1.y = fmaxf(fmaf(va1.y, i1, s1), 0.f);
            va1.z = fmaxf(fmaf(va1.z, i2, s2), 0.f);
            va1.w = fmaxf(fmaf(va1.w, i3, s3), 0.f);
        }
        As[kc + 0][ar0] = va0.x; As[kc + 1][ar0] = va0.y;
        As[kc + 2][ar0] = va0.z; As[kc + 3][ar0] = va0.w;
        As[kc + 0][ar0 + 64] = va1.x; As[kc + 1][ar0 + 64] = va1.y;
        As[kc + 2][ar0 + 64] = va1.z; As[kc + 3][ar0 + 64] = va1.w;
        float4 vb = *(const float4*)&W[(size_t)(k0 + bkr) * N + n0 + bnc];
        *(float4*)&Bs[bkr][bnc] = vb;
        __syncthreads();

        #pragma unroll
        for (int kk = 0; kk < GBK; ++kk) {
            float4 a0 = *(const float4*)&As[kk][tm0];
            float4 a1 = *(const float4*)&As[kk][tm0 + 4];
            float4 b  = *(const float4*)&Bs[kk][tn0];
            const float av[8] = {a0.x, a0.y, a0.z, a0.w, a1.x, a1.y, a1.z, a1.w};
            const float bv[4] = {b.x, b.y, b.z, b.w};
            #pragma unroll
            for (int i = 0; i < 8; ++i)
                #pragma unroll
                for (int j = 0; j < 4; ++j) acc[i][j] = fmaf(av[i], bv[j], acc[i][j]);
        }
        __syncthreads();
    }

    const float b0 = bias[n0 + tn0 + 0], b1 = bias[n0 + tn0 + 1];
    const float b2 = bias[n0 + tn0 + 2], b3 = bias[n0 + tn0 + 3];
    #pragma unroll
    for (int i = 0; i < 8; ++i) {
        int row = m0 + tm0 + i;
        float4 v = make_float4(acc[i][0] + b0, acc[i][1] + b1, acc[i][2] + b2, acc[i][3] + b3);
        if (CMODE == 0) {
            *(float4*)&C[(size_t)row * N + n0 + tn0] = v;
        } else {
            int col = n0 + tn0;
            int t = col >> 4, e = col & 15;
            *(float4*)&C[(size_t)row * 2048 + t * 32 + half * 16 + e] = v;
        }
    }
}

// ---------------- 4. BN column stats (sum / sumsq via atomics) --------------
__global__ __launch_bounds__(256) void k_bnstats(const float* __restrict__ h,
                                                 float* __restrict__ sum,
                                                 float* __restrict__ sq) {
    const int tid = threadIdx.x;
    const int r0 = blockIdx.x * 64;
    float s0 = 0, s1 = 0, s2 = 0, q0 = 0, q1 = 0, q2 = 0;
    for (int r = 0; r < 64; ++r) {
        const float* row = h + (size_t)(r0 + r) * 768;
        float v0 = row[tid], v1 = row[tid + 256], v2 = row[tid + 512];
        s0 += v0; q0 += v0 * v0;
        s1 += v1; q1 += v1 * v1;
        s2 += v2; q2 += v2 * v2;
    }
    atomicAdd(&sum[tid], s0);       atomicAdd(&sq[tid], q0);
    atomicAdd(&sum[tid + 256], s1); atomicAdd(&sq[tid + 256], q1);
    atomicAdd(&sum[tid + 512], s2); atomicAdd(&sq[tid + 512], q2);
}

__global__ __launch_bounds__(256) void k_bnfinal(const float* __restrict__ sum,
                                                 const float* __restrict__ sq,
                                                 const float* __restrict__ gamma,
                                                 const float* __restrict__ beta,
                                                 float* __restrict__ inv,
                                                 float* __restrict__ shift) {
    int c = blockIdx.x * 256 + threadIdx.x;
    if (c >= 768) return;
    float mu  = sum[c] * (1.0f / 4096.0f);
    float var = sq[c] * (1.0f / 4096.0f) - mu * mu;
    float iv  = gamma[c] / sqrtf(var + 1e-5f);
    inv[c] = iv;
    shift[c] = beta[c] - mu * iv;
}

// ---------------- 5. student-t soft assignment q ---------------------------
__global__ __launch_bounds__(256) void k_q(const float* __restrict__ z,
                                           const float* __restrict__ cluster,
                                           float* __restrict__ qout) {
    __shared__ float cl[16 * 768];
    const int tid = threadIdx.x;
    for (int i = tid; i < 16 * 768 / 4; i += 256)
        ((float4*)cl)[i] = ((const float4*)cluster)[i];
    __syncthreads();

    const int lane = tid & 63;
    const int r = blockIdx.x * 4 + (tid >> 6);
    const float* zr = z + (size_t)r * 768;

    float acc[16];
    #pragma unroll
    for (int e = 0; e < 16; ++e) acc[e] = 0.f;
    #pragma unroll
    for (int j = 0; j < 12; ++j) {
        float zv = zr[lane + 64 * j];
        #pragma unroll
        for (int e = 0; e < 16; ++e) {
            float d = zv - cl[e * 768 + lane + 64 * j];
            acc[e] = fmaf(d, d, acc[e]);
        }
    }
    #pragma unroll
    for (int e = 0; e < 16; ++e) {
        float v = acc[e];
        v += __shfl_xor(v, 32, 64);
        v += __shfl_xor(v, 16, 64);
        v += __shfl_xor(v, 8, 64);
        v += __shfl_xor(v, 4, 64);
        v += __shfl_xor(v, 2, 64);
        v += __shfl_xor(v, 1, 64);
        acc[e] = v;
    }
    float qsum = 0.f, sel = 0.f;
    #pragma unroll
    for (int e = 0; e < 16; ++e) {
        float qv = 1.0f / (1.0f + fmaxf(acc[e], 0.f));
        qsum += qv;
        if (lane == e) sel = qv;
    }
    if (lane < 16) qout[(size_t)r * 16 + lane] = sel / qsum;
}

// ---------------- launcher -------------------------------------------------
extern "C" void kernel_launch(void* const* d_in, const int* in_sizes, int n_in,
                              void* d_out, int out_size, void* d_ws, size_t ws_size,
                              hipStream_t stream) {
    const float* node_rep      = (const float*)d_in[0];
    const int*   node_batch    = (const int*)d_in[2];
    const int*   scaffold_flag = (const int*)d_in[3];
    const float* sca_ew  = (const float*)d_in[4];
    const float* sca_eb  = (const float*)d_in[5];
    const float* gro_ew  = (const float*)d_in[6];
    const float* gro_eb  = (const float*)d_in[7];
    const float* sca_w1  = (const float*)d_in[8];
    const float* sca_b1  = (const float*)d_in[9];
    const float* sca_gm  = (const float*)d_in[10];
    const float* sca_bt  = (const float*)d_in[11];
    const float* sca_w2  = (const float*)d_in[12];
    const float* sca_b2  = (const float*)d_in[13];
    const float* gro_w1  = (const float*)d_in[14];
    const float* gro_b1  = (const float*)d_in[15];
    const float* gro_gm  = (const float*)d_in[16];
    const float* gro_bt  = (const float*)d_in[17];
    const float* gro_w2  = (const float*)d_in[18];
    const float* gro_b2  = (const float*)d_in[19];
    const float* sca_cl  = (const float*)d_in[20];
    const float* gro_cl  = (const float*)d_in[21];

    float* out = (float*)d_out;
    float* clf = out + OFF_CLF;

    // ws layout: [0..15] present int + pad; then BN accumulators / params
    int*   present = (int*)d_ws;
    float* wsf  = (float*)d_ws;
    float* sum0 = wsf + 16;
    float* sq0  = sum0 + 768;
    float* sum1 = sq0 + 768;
    float* sq1  = sum1 + 768;
    float* inv0 = sq1 + 768;
    float* sh0  = inv0 + 768;
    float* inv1 = sh0 + 768;
    float* sh1  = inv1 + 768;
    hipMemsetAsync(d_ws, 0, (16 + 4 * 768) * sizeof(float), stream);

    // scratch inside d_out (clf region is overwritten last; z slots double as h buffers)
    float* sca_gate = clf;               // [4096,768]
    float* gro_gate = clf + SZ_BD;       // [4096,768]
    float* h_sca    = out + OFF_GROZ;    // temp, later overwritten by z_gro
    float* h_gro    = clf;               // overwrites sca_gate after it is consumed

    k_graphmin<<<Bg / 256, 256, 0, stream>>>(node_batch, present);
    k_pool<<<Bg, 192, 0, stream>>>(node_rep, node_batch, scaffold_flag, present,
                                   out, sca_gate, gro_gate);

    dim3 g768(4096 / GBM, 768 / GBN);
    dim3 g1024(4096 / GBM, 1024 / GBN);

    // sca gate MLP
    k_gemm<0, 0><<<g768, 256, 0, stream>>>(sca_gate, sca_w1, sca_b1, h_sca, 768, nullptr, nullptr, 0);
    k_bnstats<<<64, 256, 0, stream>>>(h_sca, sum0, sq0);
    k_bnfinal<<<3, 256, 0, stream>>>(sum0, sq0, sca_gm, sca_bt, inv0, sh0);
    k_gemm<1, 0><<<g768, 256, 0, stream>>>(h_sca, sca_w2, sca_b2, out + OFF_SCAZ, 768, inv0, sh0, 0);

    // gro gate MLP (h_gro overwrites sca_gate region, reads gro_gate region)
    k_gemm<0, 0><<<g768, 256, 0, stream>>>(gro_gate, gro_w1, gro_b1, h_gro, 768, nullptr, nullptr, 0);
    k_bnstats<<<64, 256, 0, stream>>>(h_gro, sum1, sq1);
    k_bnfinal<<<3, 256, 0, stream>>>(sum1, sq1, gro_gm, gro_bt, inv1, sh1);
    k_gemm<1, 0><<<g768, 256, 0, stream>>>(h_gro, gro_w2, gro_b2, out + OFF_GROZ, 768, inv1, sh1, 0);

    // q (reads final z slots)
    k_q<<<Bg / 4, 256, 0, stream>>>(out + OFF_SCAZ, sca_cl, out + OFF_SCAQ);
    k_q<<<Bg / 4, 256, 0, stream>>>(out + OFF_GROZ, gro_cl, out + OFF_GROQ);

    // expert logits last (overwrite clf scratch)
    k_gemm<0, 1><<<g1024, 256, 0, stream>>>(out + OFF_SCAE, sca_ew, sca_eb, clf, 1024, nullptr, nullptr, 0);
    k_gemm<0, 1><<<g1024, 256, 0, stream>>>(out + OFF_GROE, gro_ew, gro_eb, clf, 1024, nullptr, nullptr, 1);
}